// Round 8
// baseline (353.887 us; speedup 1.0000x reference)
//
#include <hip/hip_runtime.h>
#include <hip/hip_bf16.h>
#include <cstdint>

#define D_MODEL 1024
#define NUM_HEADS 16
#define HEAD_DIM 64
#define BATCH 2
#define SEQ 2048
#define MROWS (BATCH * SEQ)  // 4096

typedef __attribute__((ext_vector_type(8))) short bf16x8;   // 8 bf16 in 4 VGPRs
typedef __attribute__((ext_vector_type(4))) float f32x4;
typedef unsigned short u16;

// Q is pre-scaled by 0.125 * log2(e) at the QKV epilogue, so attention scores
// come out of the MFMA already in log2 domain: p = exp2(s) directly.
#define QSCALE (0.125f * 1.44269504f)

#if __has_builtin(__builtin_amdgcn_exp2f)
#define EXP2F(x) __builtin_amdgcn_exp2f(x)
#else
#define EXP2F(x) exp2f(x)
#endif

static __device__ __forceinline__ u16 f2bf(float f) {
    unsigned int u = __float_as_uint(f);
    unsigned int lsb = (u >> 16) & 1u;
    u += 0x7fffu + lsb;
    return (u16)(u >> 16);
}

// pack two fp32 -> two bf16 in one dword (P tiles only)
#if __has_builtin(__builtin_amdgcn_cvt_pk_bf16_f32)
static __device__ __forceinline__ unsigned pkbf(float a, float b) {
    typedef __attribute__((ext_vector_type(2))) __bf16 bf2;
    union { bf2 v; unsigned u; } cv;
    cv.v = __builtin_amdgcn_cvt_pk_bf16_f32(a, b);
    return cv.u;
}
#else
static __device__ __forceinline__ unsigned pkbf(float a, float b) {
    unsigned ua = (__float_as_uint(a) + 0x8000u) >> 16;
    unsigned ub = (__float_as_uint(b) + 0x8000u) & 0xffff0000u;
    return ua | ub;
}
#endif

static __device__ __forceinline__ void gload_lds16(const void* g, void* l) {
    // 16B/lane direct global->LDS; LDS dest = wave-uniform base + lane*16
    __builtin_amdgcn_global_load_lds((const __attribute__((address_space(1))) unsigned int*)g,
                                     (__attribute__((address_space(3))) unsigned int*)l,
                                     16, 0, 0);
}

// ---------------------------------------------------------------- convert
// One launch converts x (4 chunks of 1M) + 4 weight matrices (1M each) into
// the contiguous ws region [xb | wq | wk | wv | wo]: dst = base + which*1M.
__global__ void cvt_all(const float* __restrict__ x,
                        const float* __restrict__ w0, const float* __restrict__ w1,
                        const float* __restrict__ w2, const float* __restrict__ w3,
                        u16* __restrict__ base) {
    const int which = blockIdx.y;   // 0..7
    const int NE = D_MODEL * D_MODEL;  // 1M elements per chunk
    const float* s;
    if (which < 4)      s = x + (size_t)which * NE;
    else if (which == 4) s = w0;
    else if (which == 5) s = w1;
    else if (which == 6) s = w2;
    else                 s = w3;
    u16* dst = base + (size_t)which * NE;
    const int i = (blockIdx.x * blockDim.x + threadIdx.x) * 4;
    float4 v = *(const float4*)(s + i);
    ushort4 o;
    o.x = f2bf(v.x); o.y = f2bf(v.y); o.z = f2bf(v.z); o.w = f2bf(v.w);
    *(ushort4*)(dst + i) = o;
}

// ---------------------------------------------------------------- staged GEMM
// C[M,N] = A[M,K] * W[N,K]^T + bias. 128xBN tile, BK=64, global_load_lds
// staging with 16B-chunk XOR swizzle. MODE 0 (BN=128): fused QKV, all three
// outputs coalesced [B,H,S,64] (Q pre-scaled by QSCALE). MODE 1: fp32 row-major.
template<int BN, int MODE>
__global__ __launch_bounds__(256, 3)
void gemm_staged(const u16* __restrict__ A, const u16* __restrict__ W,
                 const float* __restrict__ b0, const float* __restrict__ b1,
                 const float* __restrict__ b2,
                 u16* __restrict__ o0, u16* __restrict__ o1, u16* __restrict__ o2,
                 float* __restrict__ of, int K, int N) {
    constexpr int WN = BN / 2;   // per-wave n extent
    constexpr int NJ = WN / 16;  // b-fragment count
    __shared__ __align__(16) u16 As[128 * 64];
    __shared__ __align__(16) u16 Bs[BN * 64];

    const int lane = threadIdx.x & 63;
    const int w    = threadIdx.x >> 6;
    const int quad = lane >> 4;
    const int l16  = lane & 15;
    const int wm = w >> 1, wn = w & 1;

    const u16* Ablk = A + (size_t)(blockIdx.y * 128) * K;
    const u16* Wblk = W + (size_t)(blockIdx.x * BN) * K;

    const int srow = lane >> 3;
    const int scol = lane & 7;

    f32x4 acc[4][NJ];
#pragma unroll
    for (int i = 0; i < 4; ++i)
#pragma unroll
        for (int j = 0; j < NJ; ++j) acc[i][j] = (f32x4){0.f, 0.f, 0.f, 0.f};

    for (int kb0 = 0; kb0 < K; kb0 += 64) {
        __syncthreads();
#pragma unroll
        for (int t = 0; t < 4; ++t) {  // A: 128 rows
            const int r  = w * 32 + t * 8 + srow;
            const int cg = scol ^ (r & 7);
            gload_lds16(Ablk + (size_t)r * K + kb0 + cg * 8, &As[(w * 32 + t * 8) * 64]);
        }
#pragma unroll
        for (int t = 0; t < BN / 32; ++t) {  // B: BN rows
            const int r  = w * (BN / 4) + t * 8 + srow;
            const int cg = scol ^ (r & 7);
            gload_lds16(Wblk + (size_t)r * K + kb0 + cg * 8, &Bs[(w * (BN / 4) + t * 8) * 64]);
        }
        __syncthreads();
#pragma unroll
        for (int ks = 0; ks < 2; ++ks) {
            bf16x8 a[4], b[NJ];
#pragma unroll
            for (int i = 0; i < 4; ++i) {
                const int ra = wm * 64 + 16 * i + l16;
                a[i] = *(const bf16x8*)&As[ra * 64 + ((ks * 4 + quad) ^ (ra & 7)) * 8];
            }
#pragma unroll
            for (int j = 0; j < NJ; ++j) {
                const int rb = wn * WN + 16 * j + l16;
                b[j] = *(const bf16x8*)&Bs[rb * 64 + ((ks * 4 + quad) ^ (rb & 7)) * 8];
            }
#pragma unroll
            for (int i = 0; i < 4; ++i)
#pragma unroll
                for (int j = 0; j < NJ; ++j)
                    acc[i][j] = __builtin_amdgcn_mfma_f32_16x16x32_bf16(a[i], b[j], acc[i][j], 0, 0, 0);
        }
    }

    const int mbase = blockIdx.y * 128 + wm * 64;
    const int nbase = blockIdx.x * BN + wn * WN;

    if (MODE == 0) {
#pragma unroll
        for (int j = 0; j < NJ; ++j) {
            const int gn = nbase + 16 * j + l16;       // 0..3071
            const int which = gn >> 10, rem = gn & 1023;
            const float bv = (which == 0 ? b0 : which == 1 ? b1 : b2)[rem];
            u16* dst = (which == 0) ? o0 : (which == 1) ? o1 : o2;
            const float scl = (which == 0) ? QSCALE : 1.0f;  // Q: x0.125*log2e
            const int h = rem >> 6, d = rem & 63;
#pragma unroll
            for (int i = 0; i < 4; ++i)
#pragma unroll
                for (int r = 0; r < 4; ++r) {
                    const int gm = mbase + 16 * i + quad * 4 + r;
                    const int bb = gm >> 11, s = gm & 2047;
                    dst[(((size_t)(bb * NUM_HEADS + h) * SEQ) + s) * 64 + d] =
                        f2bf((acc[i][j][r] + bv) * scl);
                }
        }
    } else {
#pragma unroll
        for (int j = 0; j < NJ; ++j) {
            const int gn = nbase + 16 * j + l16;
            const float bv = b0[gn];
#pragma unroll
            for (int i = 0; i < 4; ++i)
#pragma unroll
                for (int r = 0; r < 4; ++r) {
                    const int gm = mbase + 16 * i + quad * 4 + r;
                    of[(size_t)gm * N + gn] = acc[i][j][r] + bv;
                }
        }
    }
}

// ---------------------------------------------------------------- V transpose
// V [B,H,S,64] -> VT [B,H,64,S], 64x64 LDS tiles with 16B-chunk XOR swizzle.
__global__ void transpose_v(const u16* __restrict__ V, u16* __restrict__ VT) {
    __shared__ __align__(16) u16 T[64 * 64];
    const int t    = threadIdx.x;
    const int lane = t & 63, w = t >> 6;
    const int bh   = blockIdx.x & 31, sblk = blockIdx.x >> 5;
    const u16* src = V + ((size_t)bh * SEQ + sblk * 64) * 64;

#pragma unroll
    for (int p = 0; p < 2; ++p) {
        const int r = p * 32 + w * 8 + (lane >> 3);  // s-row
        const int c = lane & 7;                      // d-chunk
        bf16x8 v = *(const bf16x8*)(src + r * 64 + c * 8);
        *(bf16x8*)&T[r * 64 + ((c ^ (r & 7)) * 8)] = v;
    }
    __syncthreads();
    u16* dst = VT + ((size_t)bh * 64) * SEQ + sblk * 64;
#pragma unroll
    for (int p = 0; p < 2; ++p) {
        const int r  = p * 32 + w * 8 + (lane >> 3); // output d-row
        const int sc = lane & 7;                     // s-chunk
        union { u16 u[8]; bf16x8 v; } pk;
#pragma unroll
        for (int j = 0; j < 8; ++j)
            pk.u[j] = T[(sc * 8 + j) * 64 + (((r >> 3) ^ j) * 8) + (r & 7)];
        *(bf16x8*)(dst + (size_t)r * SEQ + sc * 8) = pk.v;
    }
}

// ---------------------------------------------------------------- attention
// IN-BLOCK SPLIT-K flash attention.
// Q (pre-scaled x0.125*log2e) [B,H,S,64], K [B,H,S,64], VT [B,H,64,S], bf16.
// 8-wave blocks, 32 q-rows/wave. Waves 0-3 (g=0) process keys 0..1023 for the
// block's 128 q-rows; waves 4-7 (g=1) process keys 1024..2047 for the SAME
// q-rows. Grid 512 -> 2 blocks/CU x 8 waves = 16 waves/CU (the R6-measured
// occupancy sweet spot) with q=32/wave LDS amortization (R7's traffic level).
// No max-subtraction => partial (O_unnorm, l) combine is an exact fp32 sum,
// done through LDS at the end (no extra kernel / memory / atomics).
// Staging: register-prefetch -> ds_write, single LDS buffer per half, two
// barriers/iter; tile t+1 global loads issue right after the commit and have
// the whole compute phase to land.
__global__ __launch_bounds__(512, 4)
void attn_kernel(const u16* __restrict__ Q, const u16* __restrict__ K,
                 const u16* __restrict__ VT, const int* __restrict__ mask,
                 u16* __restrict__ ctx) {
    __shared__ __align__(16) u16 Ks[2][64 * 64];   // [key-half][row*64]
    __shared__ __align__(16) u16 Vs[2][64 * 64];
    __shared__ __align__(16) u16 Ps[8][32 * 72];   // per-wave P; reused as O-transfer

    const int lane = threadIdx.x & 63;
    const int w    = threadIdx.x >> 6;   // 0..7
    const int g    = w >> 2;             // key half (0: keys 0..1023, 1: 1024..2047)
    const int ws4  = w & 3;              // wave within half
    const int quad = lane >> 4;
    const int l16  = lane & 15;

    const int bh = blockIdx.x & 31;      // same-head q-blocks share an XCD's L2
    const int qb = blockIdx.x >> 5;      // 0..15
    const int b  = bh >> 4;
    const int h  = bh & 15;
    const int qbase = qb * 128 + ws4 * 32;   // same q-range for g=0 and g=1

    const u16* Qh = Q + (size_t)bh * SEQ * 64;
    const u16* Kh = K + (size_t)bh * SEQ * 64;
    const u16* Vh = VT + (size_t)bh * 64 * SEQ;
    const int* mrow = mask + b * SEQ;
    const int kofs = g * 1024;           // this half's key offset

    const int srow = lane >> 3;          // 0..7
    const int scol = lane & 7;           // 16B chunk slot
    const int cg   = scol ^ srow;        // XOR-swizzled global chunk

    // register-prefetch tile 0: wave stages 16 K-rows + 16 V-rows (2 b128 each)
    uint4 kreg[2], vreg[2];
#pragma unroll
    for (int t2 = 0; t2 < 2; ++t2) {
        const int rl = 16 * ws4 + 8 * t2 + srow;
        kreg[t2] = *(const uint4*)(Kh + (size_t)(kofs + rl) * 64 + cg * 8);
        vreg[t2] = *(const uint4*)(Vh + (size_t)rl * SEQ + kofs + cg * 8);
    }

    // Q fragments: B-operand (n = query = l16, k = d = quad*8+j)
    bf16x8 qf[2][2];
#pragma unroll
    for (int iq = 0; iq < 2; ++iq)
#pragma unroll
        for (int ks = 0; ks < 2; ++ks)
            qf[iq][ks] = *(const bf16x8*)(Qh + (size_t)(qbase + 16 * iq + l16) * 64 + 32 * ks + quad * 8);

    f32x4 o[2][4];
#pragma unroll
    for (int iq = 0; iq < 2; ++iq)
#pragma unroll
        for (int id = 0; id < 4; ++id) o[iq][id] = (f32x4){0.f, 0.f, 0.f, 0.f};
    float lst[2] = {0.f, 0.f};

    unsigned short* myp = &Ps[w][0];
    const int rowsel = (lane & 48) | (quad * 4);

    for (int t = 0; t < 16; ++t) {
        __syncthreads();  // all waves done reading tile t-1 from this half's buffers

        // commit prefetched tile t regs -> LDS (slot scol holds global chunk cg)
#pragma unroll
        for (int t2 = 0; t2 < 2; ++t2) {
            const int rl = 16 * ws4 + 8 * t2 + srow;
            *(uint4*)&Ks[g][rl * 64 + scol * 8] = kreg[t2];
            *(uint4*)&Vs[g][rl * 64 + scol * 8] = vreg[t2];
        }
        // prefetch tile t+1 (lands during compute of tile t)
        if (t != 15) {
            const int kn = kofs + (t + 1) * 64;
#pragma unroll
            for (int t2 = 0; t2 < 2; ++t2) {
                const int rl = 16 * ws4 + 8 * t2 + srow;
                kreg[t2] = *(const uint4*)(Kh + (size_t)(kn + rl) * 64 + cg * 8);
                vreg[t2] = *(const uint4*)(Vh + (size_t)rl * SEQ + kn + cg * 8);
            }
        }
        __syncthreads();  // ds_writes visible to all waves of this half

        const int kstart = kofs + t * 64;
        // wave-uniform mask check: one dword per lane covers the 64-key tile
        const int mv = mrow[kstart + lane];
        const bool clean = (__ballot(mv != 0) == ~0ull);

        // K fragments from LDS: A-operand (m = key = 16ik+l16, k = d)
        bf16x8 kf[4][2];
#pragma unroll
        for (int ik = 0; ik < 4; ++ik) {
            const int row = 16 * ik + l16;
#pragma unroll
            for (int ks = 0; ks < 2; ++ks)
                kf[ik][ks] = *(const bf16x8*)&Ks[g][row * 64 + ((4 * ks + quad) ^ (row & 7)) * 8];
        }

        // S^T = K * Q^T (rows = keys, cols = queries), already in log2 domain
        f32x4 s[4][2];
#pragma unroll
        for (int ik = 0; ik < 4; ++ik)
#pragma unroll
            for (int iq = 0; iq < 2; ++iq) {
                f32x4 t0 = (f32x4){0.f, 0.f, 0.f, 0.f};
                t0 = __builtin_amdgcn_mfma_f32_16x16x32_bf16(kf[ik][0], qf[iq][0], t0, 0, 0, 0);
                t0 = __builtin_amdgcn_mfma_f32_16x16x32_bf16(kf[ik][1], qf[iq][1], t0, 0, 0, 0);
                s[ik][iq] = t0;
            }

        // V fragments from LDS: B-operand (n = d = 16id+l16, k = key)
        bf16x8 vf[4][2];
#pragma unroll
        for (int id = 0; id < 4; ++id) {
            const int row = 16 * id + l16;
#pragma unroll
            for (int ks = 0; ks < 2; ++ks)
                vf[id][ks] = *(const bf16x8*)&Vs[g][row * 64 + ((4 * ks + quad) ^ (row & 7)) * 8];
        }

        if (!clean) {  // rare: apply per-element mask fill
#pragma unroll
            for (int ik = 0; ik < 4; ++ik) {
                int4 mk = *(const int4*)(mrow + kstart + 16 * ik + quad * 4);
                const int* mp = (const int*)&mk;
#pragma unroll
                for (int r = 0; r < 4; ++r) {
                    const bool keep = (mp[r] != 0);
#pragma unroll
                    for (int iq = 0; iq < 2; ++iq)
                        s[ik][iq][r] = keep ? s[ik][iq][r] : -1e9f;
                }
            }
        }

        // p = exp2(s), accumulate col sums, pack P to LDS
#pragma unroll
        for (int iq = 0; iq < 2; ++iq) {
            float rs = 0.f;
#pragma unroll
            for (int ik = 0; ik < 4; ++ik) {
                const float p0 = EXP2F(fminf(s[ik][iq][0], 80.f));
                const float p1 = EXP2F(fminf(s[ik][iq][1], 80.f));
                const float p2 = EXP2F(fminf(s[ik][iq][2], 80.f));
                const float p3 = EXP2F(fminf(s[ik][iq][3], 80.f));
                rs += (p0 + p1) + (p2 + p3);
                uint2 pk;
                pk.x = pkbf(p0, p1);
                pk.y = pkbf(p2, p3);
                *(uint2*)(myp + (16 * iq + l16) * 72 + 16 * ik + quad * 4) = pk;
            }
            rs += __shfl_xor(rs, 16, 64);
            rs += __shfl_xor(rs, 32, 64);
            lst[iq] += rs;
        }

        // PV: A = P from per-wave LDS (same-wave DS ordering, no barrier)
#pragma unroll
        for (int ks = 0; ks < 2; ++ks) {
            bf16x8 pf[2];
#pragma unroll
            for (int iq = 0; iq < 2; ++iq)
                pf[iq] = *(const bf16x8*)(myp + (16 * iq + l16) * 72 + 32 * ks + quad * 8);
#pragma unroll
            for (int iq = 0; iq < 2; ++iq)
#pragma unroll
                for (int id = 0; id < 4; ++id)
                    o[iq][id] = __builtin_amdgcn_mfma_f32_16x16x32_bf16(pf[iq], vf[id][ks], o[iq][id], 0, 0, 0);
        }
    }

    // ---- split-K combine through LDS (exact fp32 sum; no max-rescaling) ----
    __syncthreads();                          // everyone done with Ks/Vs/Ps
    float* Ot = (float*)&Ps[0][0];            // 32 KB transfer area (fits in Ps)
    float* lt = (float*)&Ks[0][0];            // 512 B l transfer
    if (g == 1) {
#pragma unroll
        for (int iq = 0; iq < 2; ++iq) {
#pragma unroll
            for (int id = 0; id < 4; ++id)
                *(f32x4*)&Ot[ws4 * 2048 + (iq * 4 + id) * 256 + lane * 4] = o[iq][id];
            if (quad == 0) lt[ws4 * 32 + iq * 16 + l16] = lst[iq];
        }
    }
    __syncthreads();
    if (g == 0) {
#pragma unroll
        for (int iq = 0; iq < 2; ++iq) {
            const float ltot = lst[iq] + lt[ws4 * 32 + iq * 16 + l16];
            float linv[4];
#pragma unroll
            for (int r = 0; r < 4; ++r) linv[r] = 1.f / __shfl(ltot, rowsel + r, 64);
#pragma unroll
            for (int id = 0; id < 4; ++id) {
                const f32x4 o2 = *(const f32x4*)&Ot[ws4 * 2048 + (iq * 4 + id) * 256 + lane * 4];
#pragma unroll
                for (int r = 0; r < 4; ++r) {
                    const int q = qbase + 16 * iq + quad * 4 + r;
                    const int d = 16 * id + l16;
                    ctx[((size_t)(b * SEQ + q)) * D_MODEL + h * 64 + d] =
                        f2bf((o[iq][id][r] + o2[r]) * linv[r]);
                }
            }
        }
    }
}

// ---------------------------------------------------------------- launch
extern "C" void kernel_launch(void* const* d_in, const int* in_sizes, int n_in,
                              void* d_out, int out_size, void* d_ws, size_t ws_size,
                              hipStream_t stream) {
    const float* x    = (const float*)d_in[0];
    const int*   mask = (const int*)d_in[1];
    const float* Wq   = (const float*)d_in[2];
    const float* bq   = (const float*)d_in[3];
    const float* Wk   = (const float*)d_in[4];
    const float* bk   = (const float*)d_in[5];
    const float* Wv   = (const float*)d_in[6];
    const float* bv   = (const float*)d_in[7];
    const float* Wo   = (const float*)d_in[8];
    const float* bo   = (const float*)d_in[9];

    u16* xb  = (u16*)d_ws;                                   // [4096,1024]
    u16* wqb = xb  + (size_t)MROWS * D_MODEL;                // [3072,1024] fused W_qkv
    u16* wob = wqb + (size_t)3 * D_MODEL * D_MODEL;          // [1024,1024]
    u16* Qb  = wob + (size_t)D_MODEL * D_MODEL;              // [B,H,S,64]
    u16* Kb  = Qb  + (size_t)MROWS * D_MODEL;
    u16* VTb = Kb  + (size_t)MROWS * D_MODEL;                // [B,H,64,S]
    u16* ctx = VTb + (size_t)MROWS * D_MODEL;                // Vtmp, then [B,S,D] ctx

    // one conversion launch: x (4x1M) + Wq/Wk/Wv/Wo (1M each), contiguous dst
    cvt_all<<<dim3(D_MODEL * D_MODEL / 1024, 8), 256, 0, stream>>>(
        x, Wq, Wk, Wv, Wo, xb);

    // fused QKV projection: N = 3072; V written coalesced into ctx (as Vtmp)
    gemm_staged<128, 0><<<dim3(3 * D_MODEL / 128, MROWS / 128), 256, 0, stream>>>(
        xb, wqb, bq, bk, bv, Qb, Kb, ctx, nullptr, D_MODEL, 3 * D_MODEL);

    transpose_v<<<BATCH * NUM_HEADS * (SEQ / 64), 256, 0, stream>>>(ctx, VTb);

    // split-K flash attention: 512 blocks x 512 threads (128 q-rows/block)
    attn_kernel<<<BATCH * NUM_HEADS * (SEQ / 128), 512, 0, stream>>>(Qb, Kb, VTb, mask, ctx);

    gemm_staged<64, 1><<<dim3(D_MODEL / 64, MROWS / 128), 256, 0, stream>>>(
        ctx, wob, bo, nullptr, nullptr, nullptr, nullptr, nullptr,
        (float*)d_out, D_MODEL, D_MODEL);
}

// Round 9
// 189.528 us; speedup vs baseline: 1.8672x; 1.8672x over previous
//
#include <hip/hip_runtime.h>
#include <hip/hip_bf16.h>
#include <cstdint>

#define D_MODEL 1024
#define NUM_HEADS 16
#define HEAD_DIM 64
#define BATCH 2
#define SEQ 2048
#define MROWS (BATCH * SEQ)  // 4096

typedef __attribute__((ext_vector_type(8))) short bf16x8;   // 8 bf16 in 4 VGPRs
typedef __attribute__((ext_vector_type(4))) float f32x4;
typedef unsigned short u16;

// Q is pre-scaled by 0.125 * log2(e) at the QKV epilogue, so attention scores
// come out of the MFMA already in log2 domain: p = exp2(s) directly.
#define QSCALE (0.125f * 1.44269504f)

#if __has_builtin(__builtin_amdgcn_exp2f)
#define EXP2F(x) __builtin_amdgcn_exp2f(x)
#else
#define EXP2F(x) exp2f(x)
#endif

static __device__ __forceinline__ u16 f2bf(float f) {
    unsigned int u = __float_as_uint(f);
    unsigned int lsb = (u >> 16) & 1u;
    u += 0x7fffu + lsb;
    return (u16)(u >> 16);
}

// pack two fp32 -> two bf16 in one dword
#if __has_builtin(__builtin_amdgcn_cvt_pk_bf16_f32)
static __device__ __forceinline__ unsigned pkbf(float a, float b) {
    typedef __attribute__((ext_vector_type(2))) __bf16 bf2;
    union { bf2 v; unsigned u; } cv;
    cv.v = __builtin_amdgcn_cvt_pk_bf16_f32(a, b);
    return cv.u;
}
#else
static __device__ __forceinline__ unsigned pkbf(float a, float b) {
    unsigned ua = (__float_as_uint(a) + 0x8000u) >> 16;
    unsigned ub = (__float_as_uint(b) + 0x8000u) & 0xffff0000u;
    return ua | ub;
}
#endif

static __device__ __forceinline__ void gload_lds16(const void* g, void* l) {
    // 16B/lane direct global->LDS; LDS dest = wave-uniform base + lane*16
    __builtin_amdgcn_global_load_lds((const __attribute__((address_space(1))) unsigned int*)g,
                                     (__attribute__((address_space(3))) unsigned int*)l,
                                     16, 0, 0);
}

// ---------------------------------------------------------------- convert
// One launch converts x (4 chunks of 1M) + 4 weight matrices (1M each) into
// the contiguous ws region [xb | wq | wk | wv | wo]: dst = base + which*1M.
__global__ void cvt_all(const float* __restrict__ x,
                        const float* __restrict__ w0, const float* __restrict__ w1,
                        const float* __restrict__ w2, const float* __restrict__ w3,
                        u16* __restrict__ base) {
    const int which = blockIdx.y;   // 0..7
    const int NE = D_MODEL * D_MODEL;  // 1M elements per chunk
    const float* s;
    if (which < 4)      s = x + (size_t)which * NE;
    else if (which == 4) s = w0;
    else if (which == 5) s = w1;
    else if (which == 6) s = w2;
    else                 s = w3;
    u16* dst = base + (size_t)which * NE;
    const int i = (blockIdx.x * blockDim.x + threadIdx.x) * 4;
    float4 v = *(const float4*)(s + i);
    ushort4 o;
    o.x = f2bf(v.x); o.y = f2bf(v.y); o.z = f2bf(v.z); o.w = f2bf(v.w);
    *(ushort4*)(dst + i) = o;
}

// ---------------------------------------------------------------- staged GEMM
// C[M,N] = A[M,K] * W[N,K]^T + bias. 128xBN tile, BK=64, global_load_lds
// staging with 16B-chunk XOR swizzle.
// MODE 0 (BN=128, fused QKV, N=3072): blocks 0-7 -> Q (pre-scaled, coalesced
// [B,H,S,64]), 8-15 -> K (coalesced), 16-23 -> V written TRANSPOSED to
// VT[B,H,64,S] via an in-LDS 128x128 transpose (two 64-row passes).
// MODE 1: fp32 row-major out (final projection).
template<int BN, int MODE>
__global__ __launch_bounds__(256, 3)
void gemm_staged(const u16* __restrict__ A, const u16* __restrict__ W,
                 const float* __restrict__ b0, const float* __restrict__ b1,
                 const float* __restrict__ b2,
                 u16* __restrict__ o0, u16* __restrict__ o1, u16* __restrict__ o2,
                 float* __restrict__ of, int K, int N) {
    constexpr int WN = BN / 2;   // per-wave n extent
    constexpr int NJ = WN / 16;  // b-fragment count
    __shared__ __align__(16) u16 As[128 * 64];
    __shared__ __align__(16) u16 Bs[BN * 64];
    __shared__ __align__(16) u16 T[64 * 136];   // V-transpose staging (MODE 0)

    const int lane = threadIdx.x & 63;
    const int w    = threadIdx.x >> 6;
    const int quad = lane >> 4;
    const int l16  = lane & 15;
    const int wm = w >> 1, wn = w & 1;

    const u16* Ablk = A + (size_t)(blockIdx.y * 128) * K;
    const u16* Wblk = W + (size_t)(blockIdx.x * BN) * K;

    const int srow = lane >> 3;
    const int scol = lane & 7;

    f32x4 acc[4][NJ];
#pragma unroll
    for (int i = 0; i < 4; ++i)
#pragma unroll
        for (int j = 0; j < NJ; ++j) acc[i][j] = (f32x4){0.f, 0.f, 0.f, 0.f};

    for (int kb0 = 0; kb0 < K; kb0 += 64) {
        __syncthreads();
#pragma unroll
        for (int t = 0; t < 4; ++t) {  // A: 128 rows
            const int r  = w * 32 + t * 8 + srow;
            const int cg = scol ^ (r & 7);
            gload_lds16(Ablk + (size_t)r * K + kb0 + cg * 8, &As[(w * 32 + t * 8) * 64]);
        }
#pragma unroll
        for (int t = 0; t < BN / 32; ++t) {  // B: BN rows
            const int r  = w * (BN / 4) + t * 8 + srow;
            const int cg = scol ^ (r & 7);
            gload_lds16(Wblk + (size_t)r * K + kb0 + cg * 8, &Bs[(w * (BN / 4) + t * 8) * 64]);
        }
        __syncthreads();
#pragma unroll
        for (int ks = 0; ks < 2; ++ks) {
            bf16x8 a[4], b[NJ];
#pragma unroll
            for (int i = 0; i < 4; ++i) {
                const int ra = wm * 64 + 16 * i + l16;
                a[i] = *(const bf16x8*)&As[ra * 64 + ((ks * 4 + quad) ^ (ra & 7)) * 8];
            }
#pragma unroll
            for (int j = 0; j < NJ; ++j) {
                const int rb = wn * WN + 16 * j + l16;
                b[j] = *(const bf16x8*)&Bs[rb * 64 + ((ks * 4 + quad) ^ (rb & 7)) * 8];
            }
#pragma unroll
            for (int i = 0; i < 4; ++i)
#pragma unroll
                for (int j = 0; j < NJ; ++j)
                    acc[i][j] = __builtin_amdgcn_mfma_f32_16x16x32_bf16(a[i], b[j], acc[i][j], 0, 0, 0);
        }
    }

    const int mbase = blockIdx.y * 128 + wm * 64;
    const int nbase = blockIdx.x * BN + wn * WN;

    if (MODE == 0 && blockIdx.x >= 16) {
        // ---- V block: write VT[b][h][d][s] via in-LDS transpose ----
        const int mb    = blockIdx.y * 128;
        const int bb    = mb >> 11;        // batch (uniform per block)
        const int sbase = mb & 2047;       // s-range start (uniform)
#pragma unroll
        for (int p = 0; p < 2; ++p) {      // n-half pass
            __syncthreads();               // T free / previous pass consumed
            if (wn == p) {                 // 2 waves own this n-half
#pragma unroll
                for (int j = 0; j < NJ; ++j) {
                    const int nl = 16 * j + l16;          // local n within half
                    const float bv = b2[(nbase + 16 * j + l16) & 1023];
#pragma unroll
                    for (int i = 0; i < 4; ++i) {
                        const int ml = wm * 64 + 16 * i + quad * 4;
                        uint2 pk;
                        pk.x = pkbf(acc[i][j][0] + bv, acc[i][j][1] + bv);
                        pk.y = pkbf(acc[i][j][2] + bv, acc[i][j][3] + bv);
                        *(uint2*)&T[nl * 136 + ml] = pk;
                    }
                }
            }
            __syncthreads();
            // cooperative coalesced out: 64 rows (d) x 128 s; 256B/row
            const int row = threadIdx.x >> 2;                       // 0..63
            const int gn2 = blockIdx.x * 128 + p * 64 + row;
            const int rem2 = gn2 & 1023;
            const int h = rem2 >> 6, d = rem2 & 63;
            u16* dstrow = o2 + (((size_t)(bb * NUM_HEADS + h) * 64) + d) * SEQ + sbase;
#pragma unroll
            for (int k = 0; k < 4; ++k) {
                const int chunk = (threadIdx.x & 3) * 4 + k;        // 0..15
                *(uint4*)(dstrow + chunk * 8) = *(const uint4*)&T[row * 136 + chunk * 8];
            }
        }
        return;
    }

    if (MODE == 0) {
#pragma unroll
        for (int j = 0; j < NJ; ++j) {
            const int gn = nbase + 16 * j + l16;       // 0..2047 here (Q or K)
            const int which = gn >> 10, rem = gn & 1023;
            const float bv = (which == 0 ? b0 : b1)[rem];
            u16* dst = (which == 0) ? o0 : o1;
            const float scl = (which == 0) ? QSCALE : 1.0f;  // Q: x0.125*log2e
            const int h = rem >> 6, d = rem & 63;
#pragma unroll
            for (int i = 0; i < 4; ++i)
#pragma unroll
                for (int r = 0; r < 4; ++r) {
                    const int gm = mbase + 16 * i + quad * 4 + r;
                    const int bb = gm >> 11, s = gm & 2047;
                    dst[(((size_t)(bb * NUM_HEADS + h) * SEQ) + s) * 64 + d] =
                        f2bf((acc[i][j][r] + bv) * scl);
                }
        }
    } else {
#pragma unroll
        for (int j = 0; j < NJ; ++j) {
            const int gn = nbase + 16 * j + l16;
            const float bv = b0[gn];
#pragma unroll
            for (int i = 0; i < 4; ++i)
#pragma unroll
                for (int r = 0; r < 4; ++r) {
                    const int gm = mbase + 16 * i + quad * 4 + r;
                    of[(size_t)gm * N + gn] = acc[i][j][r] + bv;
                }
        }
    }
}

// ---------------------------------------------------------------- attention
// R6 configuration (measured best: 60 us, VGPR 64, no spills).
// Q (pre-scaled x0.125*log2e) [B,H,S,64], K [B,H,S,64], VT [B,H,64,S], bf16.
// 8-wave (512-thread) blocks, 16 q-rows/wave (128 q/block), grid 512 ->
// 2 blocks/CU x 8 waves = 16 waves/CU (4/SIMD) for latency hiding.
// K/VT 64-key tiles double-buffered in LDS via global_load_lds (XOR swizzle),
// one barrier per iteration. No max-subtraction: p = exp2(min(s,80));
// masked -1e9 -> exp2 -> exactly 0. #pragma unroll 2 makes `cur` static so
// all LDS addresses hoist out of the loop.
__global__ __launch_bounds__(512, 4)
void attn_kernel(const u16* __restrict__ Q, const u16* __restrict__ K,
                 const u16* __restrict__ VT, const int* __restrict__ mask,
                 u16* __restrict__ ctx) {
    __shared__ __align__(16) u16 Ks[2][64 * 64];
    __shared__ __align__(16) u16 Vs[2][64 * 64];
    __shared__ __align__(16) u16 Ps[8][16 * 72];

    const int lane = threadIdx.x & 63;
    const int w    = threadIdx.x >> 6;   // 0..7
    const int quad = lane >> 4;
    const int l16  = lane & 15;

    const int bh = blockIdx.x & 31;   // same-head q-blocks share an XCD's L2
    const int qb = blockIdx.x >> 5;   // 0..15
    const int b  = bh >> 4;
    const int h  = bh & 15;
    const int qbase = qb * 128 + w * 16;

    const u16* Qh = Q + (size_t)bh * SEQ * 64;
    const u16* Kh = K + (size_t)bh * SEQ * 64;
    const u16* Vh = VT + (size_t)bh * 64 * SEQ;
    const int* mrow = mask + b * SEQ;

    const int srow = lane >> 3;   // 0..7 row within this wave's 8-row group
    const int scol = lane & 7;    // stored 16B chunk slot
    const int cg   = scol ^ srow; // global chunk for XOR-swizzled slot

    // stage tile kb=0 into buffer 0: wave w stages rows 8w..8w+7 of each
    gload_lds16(Kh + (size_t)(8 * w + srow) * 64 + cg * 8, &Ks[0][(8 * w) * 64]);
    gload_lds16(Vh + (size_t)(8 * w + srow) * SEQ + cg * 8, &Vs[0][(8 * w) * 64]);

    // Q fragments: B-operand (n = query = l16, k = d = quad*8+j)
    bf16x8 qf[2];
#pragma unroll
    for (int ks = 0; ks < 2; ++ks)
        qf[ks] = *(const bf16x8*)(Qh + (size_t)(qbase + l16) * 64 + 32 * ks + quad * 8);

    f32x4 o[4];
#pragma unroll
    for (int id = 0; id < 4; ++id) o[id] = (f32x4){0.f, 0.f, 0.f, 0.f};
    float lst = 0.f;

    unsigned short* myp = &Ps[w][0];
    const int rowsel = (lane & 48) | (quad * 4);

#pragma unroll 2
    for (int kb = 0; kb < 32; ++kb) {
        const int cur = kb & 1;
        __syncthreads();  // drains stage(kb); all waves done with buf cur^1

        if (kb != 31) {   // stage kb+1 into the other buffer (in flight all iter)
            const int kn = (kb + 1) * 64;
            gload_lds16(Kh + (size_t)(kn + 8 * w + srow) * 64 + cg * 8,
                        &Ks[cur ^ 1][(8 * w) * 64]);
            gload_lds16(Vh + (size_t)(8 * w + srow) * SEQ + kn + cg * 8,
                        &Vs[cur ^ 1][(8 * w) * 64]);
        }

        const int kstart = kb * 64;
        // wave-uniform mask check: one dword per lane covers the 64-key tile
        const int mv = mrow[kstart + lane];
        const bool clean = (__ballot(mv != 0) == ~0ull);

        // K fragments from LDS: A-operand (m = key = 16ik+l16, k = d)
        bf16x8 kf[4][2];
#pragma unroll
        for (int ik = 0; ik < 4; ++ik) {
            const int row = 16 * ik + l16;
#pragma unroll
            for (int ks = 0; ks < 2; ++ks)
                kf[ik][ks] = *(const bf16x8*)&Ks[cur][row * 64 + ((4 * ks + quad) ^ (row & 7)) * 8];
        }

        // S^T = K * Q^T (rows = keys, cols = queries), already in log2 domain
        f32x4 s[4];
#pragma unroll
        for (int ik = 0; ik < 4; ++ik) {
            f32x4 t = (f32x4){0.f, 0.f, 0.f, 0.f};
            t = __builtin_amdgcn_mfma_f32_16x16x32_bf16(kf[ik][0], qf[0], t, 0, 0, 0);
            t = __builtin_amdgcn_mfma_f32_16x16x32_bf16(kf[ik][1], qf[1], t, 0, 0, 0);
            s[ik] = t;
        }

        // V fragments from LDS: B-operand (n = d = 16id+l16, k = key)
        bf16x8 vf[4][2];
#pragma unroll
        for (int id = 0; id < 4; ++id) {
            const int row = 16 * id + l16;
#pragma unroll
            for (int ks = 0; ks < 2; ++ks)
                vf[id][ks] = *(const bf16x8*)&Vs[cur][row * 64 + ((4 * ks + quad) ^ (row & 7)) * 8];
        }

        if (!clean) {  // rare: apply per-element mask fill
#pragma unroll
            for (int ik = 0; ik < 4; ++ik) {
                int4 mk = *(const int4*)(mrow + kstart + 16 * ik + quad * 4);
                const int* mp = (const int*)&mk;
#pragma unroll
                for (int r = 0; r < 4; ++r)
                    s[ik][r] = (mp[r] != 0) ? s[ik][r] : -1e9f;
            }
        }

        // p = exp2(s), accumulate row sums, pack P to LDS
        float rs = 0.f;
#pragma unroll
        for (int ik = 0; ik < 4; ++ik) {
            const float p0 = EXP2F(fminf(s[ik][0], 80.f));
            const float p1 = EXP2F(fminf(s[ik][1], 80.f));
            const float p2 = EXP2F(fminf(s[ik][2], 80.f));
            const float p3 = EXP2F(fminf(s[ik][3], 80.f));
            rs += (p0 + p1) + (p2 + p3);
            uint2 pk;
            pk.x = pkbf(p0, p1);
            pk.y = pkbf(p2, p3);
            *(uint2*)(myp + l16 * 72 + 16 * ik + quad * 4) = pk;
        }
        rs += __shfl_xor(rs, 16, 64);
        rs += __shfl_xor(rs, 32, 64);
        lst += rs;

        // PV: A = P from per-wave LDS (same-wave DS ordering, no barrier)
#pragma unroll
        for (int ks = 0; ks < 2; ++ks) {
            bf16x8 pf = *(const bf16x8*)(myp + l16 * 72 + 32 * ks + quad * 8);
#pragma unroll
            for (int id = 0; id < 4; ++id)
                o[id] = __builtin_amdgcn_mfma_f32_16x16x32_bf16(pf, vf[id][ks], o[id], 0, 0, 0);
        }
    }

    // epilogue: divide by softmax sum (l lives per-col -> remap to rows)
    float linv[4];
#pragma unroll
    for (int r = 0; r < 4; ++r) linv[r] = 1.f / __shfl(lst, rowsel + r, 64);
#pragma unroll
    for (int id = 0; id < 4; ++id)
#pragma unroll
        for (int r = 0; r < 4; ++r) {
            const int q = qbase + quad * 4 + r;
            const int d = 16 * id + l16;
            ctx[((size_t)(b * SEQ + q)) * D_MODEL + h * 64 + d] = f2bf(o[id][r] * linv[r]);
        }
}

// ---------------------------------------------------------------- launch
extern "C" void kernel_launch(void* const* d_in, const int* in_sizes, int n_in,
                              void* d_out, int out_size, void* d_ws, size_t ws_size,
                              hipStream_t stream) {
    const float* x    = (const float*)d_in[0];
    const int*   mask = (const int*)d_in[1];
    const float* Wq   = (const float*)d_in[2];
    const float* bq   = (const float*)d_in[3];
    const float* Wk   = (const float*)d_in[4];
    const float* bk   = (const float*)d_in[5];
    const float* Wv   = (const float*)d_in[6];
    const float* bv   = (const float*)d_in[7];
    const float* Wo   = (const float*)d_in[8];
    const float* bo   = (const float*)d_in[9];

    u16* xb  = (u16*)d_ws;                                   // [4096,1024]
    u16* wqb = xb  + (size_t)MROWS * D_MODEL;                // [3072,1024] fused W_qkv
    u16* wob = wqb + (size_t)3 * D_MODEL * D_MODEL;          // [1024,1024]
    u16* Qb  = wob + (size_t)D_MODEL * D_MODEL;              // [B,H,S,64]
    u16* Kb  = Qb  + (size_t)MROWS * D_MODEL;
    u16* VTb = Kb  + (size_t)MROWS * D_MODEL;                // [B,H,64,S]
    u16* ctx = VTb + (size_t)MROWS * D_MODEL;                // [B,S,D]

    // one conversion launch: x (4x1M) + Wq/Wk/Wv/Wo (1M each), contiguous dst
    cvt_all<<<dim3(D_MODEL * D_MODEL / 1024, 8), 256, 0, stream>>>(
        x, Wq, Wk, Wv, Wo, xb);

    // fused QKV projection: N = 3072; V written transposed directly to VTb
    gemm_staged<128, 0><<<dim3(3 * D_MODEL / 128, MROWS / 128), 256, 0, stream>>>(
        xb, wqb, bq, bk, bv, Qb, Kb, VTb, nullptr, D_MODEL, 3 * D_MODEL);

    attn_kernel<<<BATCH * NUM_HEADS * (SEQ / 128), 512, 0, stream>>>(Qb, Kb, VTb, mask, ctx);

    gemm_staged<64, 1><<<dim3(D_MODEL / 64, MROWS / 128), 256, 0, stream>>>(
        ctx, wob, bo, nullptr, nullptr, nullptr, nullptr, nullptr,
        (float*)d_out, D_MODEL, D_MODEL);
}